// Round 2
// baseline (1226.673 us; speedup 1.0000x reference)
//
#include <hip/hip_runtime.h>
#include <hip/hip_bf16.h>
#include <math.h>

#define N_NODES 16384
#define TI 32      // i-rows per adjacency block
#define TJ 1024    // j-cols per adjacency block (256 threads x 4)

// ---------------------------------------------------------------------------
// Detect whether `batch` is int64 (jax x64 enabled) or int32 (default).
// batch is sorted non-decreasing in [0,64). Read as int32:
//   int32 case -> strictly non-decreasing, no decrease anywhere.
//   int64 case -> [b0,0,b1,0,...]; once b_k >= 1 we see a decrease.
// Writes flag (0 = int32, 1 = int64) to d_ws.
// ---------------------------------------------------------------------------
__global__ __launch_bounds__(256) void detect_i64_kernel(const int* __restrict__ b,
                                                         int* __restrict__ flag) {
    __shared__ int dec;
    if (threadIdx.x == 0) dec = 0;
    __syncthreads();
    int local = 0;
    for (int k = threadIdx.x; k < N_NODES - 1; k += 256)
        if (b[k + 1] < b[k]) local = 1;
    if (local) atomicOr(&dec, 1);
    __syncthreads();
    if (threadIdx.x == 0) flag[0] = dec;
}

// ---------------------------------------------------------------------------
// MLP: out[i] = silu(emb[z[i]] @ w1 + b1) @ w2 + b2
// One wave (64 lanes) per node; lane j owns column j of w1 (128x64).
// ---------------------------------------------------------------------------
__global__ __launch_bounds__(256) void mlp_kernel(const int* __restrict__ z,
                                                  const float* __restrict__ emb,
                                                  const float* __restrict__ w1,
                                                  const float* __restrict__ b1,
                                                  const float* __restrict__ w2,
                                                  const float* __restrict__ b2,
                                                  float* __restrict__ out) {
    const int lane = threadIdx.x & 63;
    const int wave = threadIdx.x >> 6;
    const int i = blockIdx.x * 4 + wave;
    if (i >= N_NODES) return;

    const float4* erow = (const float4*)(emb + (size_t)z[i] * 128);
    float acc = b1[lane];
#pragma unroll 8
    for (int k4 = 0; k4 < 32; k4++) {
        float4 e = erow[k4];
        int k = k4 * 4;
        acc = fmaf(e.x, w1[(k + 0) * 64 + lane], acc);
        acc = fmaf(e.y, w1[(k + 1) * 64 + lane], acc);
        acc = fmaf(e.z, w1[(k + 2) * 64 + lane], acc);
        acc = fmaf(e.w, w1[(k + 3) * 64 + lane], acc);
    }
    float h = acc / (1.0f + expf(-acc));   // silu
    float t = h * w2[lane];
#pragma unroll
    for (int off = 32; off >= 1; off >>= 1)
        t += __shfl_xor(t, off, 64);
    if (lane == 0) out[i] = t + b2[0];
}

// ---------------------------------------------------------------------------
// Adjacency: adj[i,j] = (d2 < 64) && (batch[i]==batch[j]) && (i != j), as
// 1.0f/0.0f. d2 replicates numpy f32 semantics EXACTLY:
//   sq[i]  = rn(rn(x*x + y*y) + z*z)            (elementwise mul, pairwise add)
//   dot    = fma(z,z', fma(y,y', rn(x*x')))     (BLAS sgemm sequential-FMA)
//   d2     = rn(rn(sq_i + sq_j) - 2*dot)
// Block = TI(32) rows x TJ(1024) cols; thread holds 4 cols in registers,
// i-tile staged in LDS; float4 stores, 4 KB contiguous per row-iteration.
// ---------------------------------------------------------------------------
__global__ __launch_bounds__(256) void adj_kernel(const float* __restrict__ pos,
                                                  const void* __restrict__ batch_raw,
                                                  const int* __restrict__ flag,
                                                  float* __restrict__ adj) {
    __shared__ float s_x[TI], s_y[TI], s_z[TI], s_sq[TI];
    __shared__ int   s_b[TI];

    const bool is64 = (flag[0] != 0);
    const int* b32 = (const int*)batch_raw;
    const long long* b64 = (const long long*)batch_raw;

    const int t     = threadIdx.x;
    const int jbase = blockIdx.x * TJ;
    const int ibase = blockIdx.y * TI;

    if (t < TI) {
        int i = ibase + t;
        float x = pos[i * 3 + 0], y = pos[i * 3 + 1], z = pos[i * 3 + 2];
        s_x[t] = x; s_y[t] = y; s_z[t] = z;
        s_sq[t] = __fadd_rn(__fadd_rn(__fmul_rn(x, x), __fmul_rn(y, y)), __fmul_rn(z, z));
        s_b[t] = is64 ? (int)b64[i] : b32[i];
    }
    __syncthreads();

    const int j0 = jbase + t * 4;
    // 4 consecutive j positions: 12 contiguous floats -> 3 aligned float4 loads.
    const float4* p4 = (const float4*)(pos + (size_t)jbase * 3);
    float4 A = p4[t * 3 + 0];
    float4 B = p4[t * 3 + 1];
    float4 C = p4[t * 3 + 2];
    const float xj[4] = {A.x, A.w, B.z, C.y};
    const float yj[4] = {A.y, B.x, B.w, C.z};
    const float zj[4] = {A.z, B.y, C.x, C.w};

    float sqj[4];
#pragma unroll
    for (int m = 0; m < 4; m++)
        sqj[m] = __fadd_rn(__fadd_rn(__fmul_rn(xj[m], xj[m]), __fmul_rn(yj[m], yj[m])),
                           __fmul_rn(zj[m], zj[m]));

    int bj[4];
    if (is64) {
#pragma unroll
        for (int m = 0; m < 4; m++) bj[m] = (int)b64[j0 + m];
    } else {
        int4 bb = *(const int4*)(b32 + j0);
        bj[0] = bb.x; bj[1] = bb.y; bj[2] = bb.z; bj[3] = bb.w;
    }

    float* orow = adj + (size_t)ibase * N_NODES + j0;
#pragma unroll 4
    for (int ii = 0; ii < TI; ii++) {
        const float xi = s_x[ii], yi = s_y[ii], zi = s_z[ii], sqi = s_sq[ii];
        const int bi = s_b[ii];
        const int i = ibase + ii;
        float r[4];
#pragma unroll
        for (int m = 0; m < 4; m++) {
            float dot = fmaf(zi, zj[m], fmaf(yi, yj[m], __fmul_rn(xi, xj[m])));
            float d2 = __fsub_rn(__fadd_rn(sqi, sqj[m]), __fadd_rn(dot, dot));
            bool v = (d2 < 64.0f) && (bi == bj[m]) && (i != j0 + m);
            r[m] = v ? 1.0f : 0.0f;
        }
        float4 rv = make_float4(r[0], r[1], r[2], r[3]);
        *(float4*)(orow + (size_t)ii * N_NODES) = rv;
    }
}

extern "C" void kernel_launch(void* const* d_in, const int* in_sizes, int n_in,
                              void* d_out, int out_size, void* d_ws, size_t ws_size,
                              hipStream_t stream) {
    const int*   z     = (const int*)d_in[0];
    const void*  batch = d_in[1];           // int32 or int64, detected at runtime
    const float* pos   = (const float*)d_in[2];
    const float* emb   = (const float*)d_in[3];
    const float* w1    = (const float*)d_in[4];
    const float* b1    = (const float*)d_in[5];
    const float* w2    = (const float*)d_in[6];
    const float* b2    = (const float*)d_in[7];

    float* out = (float*)d_out;             // [16384] node outputs
    float* adj = out + N_NODES;             // [16384 x 16384] adjacency as 0/1 floats
    int* flag = (int*)d_ws;

    detect_i64_kernel<<<1, 256, 0, stream>>>((const int*)batch, flag);
    mlp_kernel<<<N_NODES / 4, 256, 0, stream>>>(z, emb, w1, b1, w2, b2, out);
    adj_kernel<<<dim3(N_NODES / TJ, N_NODES / TI), 256, 0, stream>>>(pos, batch, flag, adj);
}

// Round 3
// 1119.169 us; speedup vs baseline: 1.0961x; 1.0961x over previous
//
#include <hip/hip_runtime.h>
#include <hip/hip_bf16.h>
#include <math.h>

#define N_NODES 16384
#define TI 64      // i-rows per adjacency block
#define TJ 1024    // j-cols per adjacency block (256 threads x 4)

typedef float vf4 __attribute__((ext_vector_type(4)));

// ---------------------------------------------------------------------------
// MLP: out[i] = silu(emb[z[i]] @ w1 + b1) @ w2 + b2
// One wave (64 lanes) per node; lane j owns column j of w1 (128x64).
// Block 0 additionally detects whether `batch` is int64 (jax x64) or int32:
// batch is sorted non-decreasing in [0,64). Read as int32: the int32 case has
// no decrease anywhere; the int64 case interleaves zeros -> decreases appear.
// Writes flag (0 = int32, 1 = int64) to d_ws; consumed by adj_kernel (same
// stream, ordered).
// ---------------------------------------------------------------------------
__global__ __launch_bounds__(256) void mlp_kernel(const int* __restrict__ z,
                                                  const float* __restrict__ emb,
                                                  const float* __restrict__ w1,
                                                  const float* __restrict__ b1,
                                                  const float* __restrict__ w2,
                                                  const float* __restrict__ b2,
                                                  const int* __restrict__ batch32,
                                                  int* __restrict__ flag,
                                                  float* __restrict__ out) {
    if (blockIdx.x == 0) {
        __shared__ int dec;
        if (threadIdx.x == 0) dec = 0;
        __syncthreads();
        int local = 0;
        for (int k = threadIdx.x; k < N_NODES - 1; k += 256)
            if (batch32[k + 1] < batch32[k]) local = 1;
        if (local) atomicOr(&dec, 1);
        __syncthreads();
        if (threadIdx.x == 0) flag[0] = dec;
    }

    const int lane = threadIdx.x & 63;
    const int wave = threadIdx.x >> 6;
    const int i = blockIdx.x * 4 + wave;
    if (i >= N_NODES) return;

    const float4* erow = (const float4*)(emb + (size_t)z[i] * 128);
    float acc = b1[lane];
#pragma unroll 8
    for (int k4 = 0; k4 < 32; k4++) {
        float4 e = erow[k4];
        int k = k4 * 4;
        acc = fmaf(e.x, w1[(k + 0) * 64 + lane], acc);
        acc = fmaf(e.y, w1[(k + 1) * 64 + lane], acc);
        acc = fmaf(e.z, w1[(k + 2) * 64 + lane], acc);
        acc = fmaf(e.w, w1[(k + 3) * 64 + lane], acc);
    }
    float h = acc / (1.0f + expf(-acc));   // silu
    float t = h * w2[lane];
#pragma unroll
    for (int off = 32; off >= 1; off >>= 1)
        t += __shfl_xor(t, off, 64);
    if (lane == 0) out[i] = t + b2[0];
}

// ---------------------------------------------------------------------------
// Adjacency: adj[i,j] = (d2 < 64) && (batch[i]==batch[j]) && (i != j), as
// 1.0f/0.0f. d2 replicates numpy f32 semantics EXACTLY:
//   sq[i]  = rn(rn(x*x + y*y) + z*z)            (elementwise mul, pairwise add)
//   dot    = fma(z,z', fma(y,y', rn(x*x')))     (BLAS sgemm sequential-FMA)
//   d2     = rn(rn(sq_i + sq_j) - 2*dot)
// Block = TI(64) rows x TJ(1024) cols; thread holds 4 cols in registers,
// i-tile packed {x,y,z,sq} in LDS (1 ds_read_b128 + 1 b32 per row).
// DIAG template: the i!=j check only exists for the 1/16 of blocks whose row
// panel intersects the column panel. Nontemporal float4 stores (1 GB stream;
// bypass L2 write-allocate).
// ---------------------------------------------------------------------------
template <bool DIAG>
__device__ __forceinline__ void adj_rows(const vf4* __restrict__ s_p,
                                         const int* __restrict__ s_b,
                                         const float xj[4], const float yj[4],
                                         const float zj[4], const float sqj[4],
                                         const int bj[4],
                                         int ibase, int j0,
                                         float* __restrict__ orow) {
#pragma unroll 4
    for (int ii = 0; ii < TI; ii++) {
        vf4 p = s_p[ii];
        const float xi = p.x, yi = p.y, zi = p.z, sqi = p.w;
        const int bi = s_b[ii];
        float r[4];
#pragma unroll
        for (int m = 0; m < 4; m++) {
            float dot = fmaf(zi, zj[m], fmaf(yi, yj[m], __fmul_rn(xi, xj[m])));
            float d2 = __fsub_rn(__fadd_rn(sqi, sqj[m]), __fadd_rn(dot, dot));
            bool v = (d2 < 64.0f) && (bi == bj[m]);
            if (DIAG) v = v && ((ibase + ii) != (j0 + m));
            r[m] = v ? 1.0f : 0.0f;
        }
        vf4 rv = {r[0], r[1], r[2], r[3]};
        __builtin_nontemporal_store(rv, (vf4*)(orow + (size_t)ii * N_NODES));
    }
}

__global__ __launch_bounds__(256) void adj_kernel(const float* __restrict__ pos,
                                                  const void* __restrict__ batch_raw,
                                                  const int* __restrict__ flag,
                                                  float* __restrict__ adj) {
    __shared__ vf4 s_p[TI];
    __shared__ int s_b[TI];

    const bool is64 = (flag[0] != 0);
    const int* b32 = (const int*)batch_raw;
    const long long* b64 = (const long long*)batch_raw;

    const int t     = threadIdx.x;
    const int jbase = blockIdx.x * TJ;
    const int ibase = blockIdx.y * TI;

    if (t < TI) {
        int i = ibase + t;
        float x = pos[i * 3 + 0], y = pos[i * 3 + 1], z = pos[i * 3 + 2];
        vf4 p;
        p.x = x; p.y = y; p.z = z;
        p.w = __fadd_rn(__fadd_rn(__fmul_rn(x, x), __fmul_rn(y, y)), __fmul_rn(z, z));
        s_p[t] = p;
        s_b[t] = is64 ? (int)b64[i] : b32[i];
    }
    __syncthreads();

    const int j0 = jbase + t * 4;
    // 4 consecutive j positions: 12 contiguous floats -> 3 aligned float4 loads.
    const float4* p4 = (const float4*)(pos + (size_t)jbase * 3);
    float4 A = p4[t * 3 + 0];
    float4 B = p4[t * 3 + 1];
    float4 C = p4[t * 3 + 2];
    const float xj[4] = {A.x, A.w, B.z, C.y};
    const float yj[4] = {A.y, B.x, B.w, C.z};
    const float zj[4] = {A.z, B.y, C.x, C.w};

    float sqj[4];
#pragma unroll
    for (int m = 0; m < 4; m++)
        sqj[m] = __fadd_rn(__fadd_rn(__fmul_rn(xj[m], xj[m]), __fmul_rn(yj[m], yj[m])),
                           __fmul_rn(zj[m], zj[m]));

    int bj[4];
    if (is64) {
#pragma unroll
        for (int m = 0; m < 4; m++) bj[m] = (int)b64[j0 + m];
    } else {
        int4 bb = *(const int4*)(b32 + j0);
        bj[0] = bb.x; bj[1] = bb.y; bj[2] = bb.z; bj[3] = bb.w;
    }

    float* orow = adj + (size_t)ibase * N_NODES + j0;
    // Row panel [ibase, ibase+64) intersects col panel [jbase, jbase+1024)
    // iff ibase - jbase in [0, TJ) (both are aligned multiples, TI <= TJ).
    if ((unsigned)(ibase - jbase) < (unsigned)TJ)
        adj_rows<true>(s_p, s_b, xj, yj, zj, sqj, bj, ibase, j0, orow);
    else
        adj_rows<false>(s_p, s_b, xj, yj, zj, sqj, bj, ibase, j0, orow);
}

extern "C" void kernel_launch(void* const* d_in, const int* in_sizes, int n_in,
                              void* d_out, int out_size, void* d_ws, size_t ws_size,
                              hipStream_t stream) {
    const int*   z     = (const int*)d_in[0];
    const void*  batch = d_in[1];           // int32 or int64, detected at runtime
    const float* pos   = (const float*)d_in[2];
    const float* emb   = (const float*)d_in[3];
    const float* w1    = (const float*)d_in[4];
    const float* b1    = (const float*)d_in[5];
    const float* w2    = (const float*)d_in[6];
    const float* b2    = (const float*)d_in[7];

    float* out = (float*)d_out;             // [16384] node outputs
    float* adj = out + N_NODES;             // [16384 x 16384] adjacency as 0/1 floats
    int* flag = (int*)d_ws;

    mlp_kernel<<<N_NODES / 4, 256, 0, stream>>>(z, emb, w1, b1, w2, b2,
                                                (const int*)batch, flag, out);
    adj_kernel<<<dim3(N_NODES / TJ, N_NODES / TI), 256, 0, stream>>>(pos, batch, flag, adj);
}

// Round 4
// 1117.691 us; speedup vs baseline: 1.0975x; 1.0013x over previous
//
#include <hip/hip_runtime.h>
#include <hip/hip_bf16.h>
#include <math.h>

#define N_NODES 16384
#define TI 64      // i-rows per adjacency block
#define TJ 1024    // j-cols per adjacency block (256 threads x 4)

typedef float vf4 __attribute__((ext_vector_type(4)));

// ---------------------------------------------------------------------------
// MLP: out[i] = silu(emb[z[i]] @ w1 + b1) @ w2 + b2
// One wave (64 lanes) per node; lane j owns column j of w1 (128x64).
// Block 0 additionally detects whether `batch` is int64 (jax x64) or int32:
// batch is sorted non-decreasing in [0,64). Read as int32: the int32 case has
// no decrease anywhere; the int64 case interleaves zeros -> decreases appear.
// Writes flag (0 = int32, 1 = int64) to d_ws; consumed by adj_kernel (same
// stream, ordered).
// ---------------------------------------------------------------------------
__global__ __launch_bounds__(256) void mlp_kernel(const int* __restrict__ z,
                                                  const float* __restrict__ emb,
                                                  const float* __restrict__ w1,
                                                  const float* __restrict__ b1,
                                                  const float* __restrict__ w2,
                                                  const float* __restrict__ b2,
                                                  const int* __restrict__ batch32,
                                                  int* __restrict__ flag,
                                                  float* __restrict__ out) {
    if (blockIdx.x == 0) {
        __shared__ int dec;
        if (threadIdx.x == 0) dec = 0;
        __syncthreads();
        int local = 0;
        for (int k = threadIdx.x; k < N_NODES - 1; k += 256)
            if (batch32[k + 1] < batch32[k]) local = 1;
        if (local) atomicOr(&dec, 1);
        __syncthreads();
        if (threadIdx.x == 0) flag[0] = dec;
    }

    const int lane = threadIdx.x & 63;
    const int wave = threadIdx.x >> 6;
    const int i = blockIdx.x * 4 + wave;
    if (i >= N_NODES) return;

    const float4* erow = (const float4*)(emb + (size_t)z[i] * 128);
    float acc = b1[lane];
#pragma unroll 8
    for (int k4 = 0; k4 < 32; k4++) {
        float4 e = erow[k4];
        int k = k4 * 4;
        acc = fmaf(e.x, w1[(k + 0) * 64 + lane], acc);
        acc = fmaf(e.y, w1[(k + 1) * 64 + lane], acc);
        acc = fmaf(e.z, w1[(k + 2) * 64 + lane], acc);
        acc = fmaf(e.w, w1[(k + 3) * 64 + lane], acc);
    }
    float h = acc / (1.0f + expf(-acc));   // silu
    float t = h * w2[lane];
#pragma unroll
    for (int off = 32; off >= 1; off >>= 1)
        t += __shfl_xor(t, off, 64);
    if (lane == 0) out[i] = t + b2[0];
}

// ---------------------------------------------------------------------------
// Adjacency: adj[i,j] = (d2 < 64) && (batch[i]==batch[j]) && (i != j), as
// 1.0f/0.0f.
//
// FAST PATH (~94% of blocks): batch is SORTED, so the batch range of the
// block's 64-row i-panel is [batch[ibase], batch[ibase+63]] and of its
// 1024-col j-panel is [batch[jbase], batch[jbase+1023]]. If the two ranges
// are disjoint, every element of the tile is 0 regardless of distance ->
// stream nontemporal zero-float4 stores (same structure as the 6.25 TB/s
// rocclr fill kernel). Branch is block-uniform.
//
// COMPUTE PATH: d2 replicates numpy f32 semantics EXACTLY:
//   sq[i]  = rn(rn(x*x + y*y) + z*z)            (elementwise mul, pairwise add)
//   dot    = fma(z,z', fma(y,y', rn(x*x')))     (BLAS sgemm sequential-FMA)
//   d2     = rn(rn(sq_i + sq_j) - 2*dot)
// i-tile packed {x,y,z,sq} in LDS; DIAG template drops the i!=j compare for
// blocks whose row panel cannot intersect the column panel.
// ---------------------------------------------------------------------------
template <bool DIAG>
__device__ __forceinline__ void adj_rows(const vf4* __restrict__ s_p,
                                         const int* __restrict__ s_b,
                                         const float xj[4], const float yj[4],
                                         const float zj[4], const float sqj[4],
                                         const int bj[4],
                                         int ibase, int j0,
                                         float* __restrict__ orow) {
#pragma unroll 4
    for (int ii = 0; ii < TI; ii++) {
        vf4 p = s_p[ii];
        const float xi = p.x, yi = p.y, zi = p.z, sqi = p.w;
        const int bi = s_b[ii];
        float r[4];
#pragma unroll
        for (int m = 0; m < 4; m++) {
            float dot = fmaf(zi, zj[m], fmaf(yi, yj[m], __fmul_rn(xi, xj[m])));
            float d2 = __fsub_rn(__fadd_rn(sqi, sqj[m]), __fadd_rn(dot, dot));
            bool v = (d2 < 64.0f) && (bi == bj[m]);
            if (DIAG) v = v && ((ibase + ii) != (j0 + m));
            r[m] = v ? 1.0f : 0.0f;
        }
        vf4 rv = {r[0], r[1], r[2], r[3]};
        __builtin_nontemporal_store(rv, (vf4*)(orow + (size_t)ii * N_NODES));
    }
}

__global__ __launch_bounds__(256) void adj_kernel(const float* __restrict__ pos,
                                                  const void* __restrict__ batch_raw,
                                                  const int* __restrict__ flag,
                                                  float* __restrict__ adj) {
    __shared__ vf4 s_p[TI];
    __shared__ int s_b[TI];

    const bool is64 = (flag[0] != 0);
    const int* b32 = (const int*)batch_raw;
    const long long* b64 = (const long long*)batch_raw;

    const int t     = threadIdx.x;
    const int jbase = blockIdx.x * TJ;
    const int ibase = blockIdx.y * TI;
    const int j0    = jbase + t * 4;
    float* orow = adj + (size_t)ibase * N_NODES + j0;

    // --- Panel batch ranges (sorted batch => endpoints bound the range) ---
    int b_lo, b_hi, c_lo, c_hi;
    if (is64) {
        b_lo = (int)b64[ibase];  b_hi = (int)b64[ibase + TI - 1];
        c_lo = (int)b64[jbase];  c_hi = (int)b64[jbase + TJ - 1];
    } else {
        b_lo = b32[ibase];  b_hi = b32[ibase + TI - 1];
        c_lo = b32[jbase];  c_hi = b32[jbase + TJ - 1];
    }

    if (b_hi < c_lo || c_hi < b_lo) {
        // Fast path: entire 64x1024 tile is zero. Pure store stream.
        vf4 zero = {0.0f, 0.0f, 0.0f, 0.0f};
#pragma unroll 8
        for (int ii = 0; ii < TI; ii++)
            __builtin_nontemporal_store(zero, (vf4*)(orow + (size_t)ii * N_NODES));
        return;
    }

    // --- Compute path ---
    if (t < TI) {
        int i = ibase + t;
        float x = pos[i * 3 + 0], y = pos[i * 3 + 1], z = pos[i * 3 + 2];
        vf4 p;
        p.x = x; p.y = y; p.z = z;
        p.w = __fadd_rn(__fadd_rn(__fmul_rn(x, x), __fmul_rn(y, y)), __fmul_rn(z, z));
        s_p[t] = p;
        s_b[t] = is64 ? (int)b64[i] : b32[i];
    }
    __syncthreads();

    // 4 consecutive j positions: 12 contiguous floats -> 3 aligned float4 loads.
    const float4* p4 = (const float4*)(pos + (size_t)jbase * 3);
    float4 A = p4[t * 3 + 0];
    float4 B = p4[t * 3 + 1];
    float4 C = p4[t * 3 + 2];
    const float xj[4] = {A.x, A.w, B.z, C.y};
    const float yj[4] = {A.y, B.x, B.w, C.z};
    const float zj[4] = {A.z, B.y, C.x, C.w};

    float sqj[4];
#pragma unroll
    for (int m = 0; m < 4; m++)
        sqj[m] = __fadd_rn(__fadd_rn(__fmul_rn(xj[m], xj[m]), __fmul_rn(yj[m], yj[m])),
                           __fmul_rn(zj[m], zj[m]));

    int bj[4];
    if (is64) {
#pragma unroll
        for (int m = 0; m < 4; m++) bj[m] = (int)b64[j0 + m];
    } else {
        int4 bb = *(const int4*)(b32 + j0);
        bj[0] = bb.x; bj[1] = bb.y; bj[2] = bb.z; bj[3] = bb.w;
    }

    // Row panel [ibase, ibase+64) intersects col panel [jbase, jbase+1024)
    // iff ibase - jbase in [0, TJ) (both are aligned multiples, TI <= TJ).
    if ((unsigned)(ibase - jbase) < (unsigned)TJ)
        adj_rows<true>(s_p, s_b, xj, yj, zj, sqj, bj, ibase, j0, orow);
    else
        adj_rows<false>(s_p, s_b, xj, yj, zj, sqj, bj, ibase, j0, orow);
}

extern "C" void kernel_launch(void* const* d_in, const int* in_sizes, int n_in,
                              void* d_out, int out_size, void* d_ws, size_t ws_size,
                              hipStream_t stream) {
    const int*   z     = (const int*)d_in[0];
    const void*  batch = d_in[1];           // int32 or int64, detected at runtime
    const float* pos   = (const float*)d_in[2];
    const float* emb   = (const float*)d_in[3];
    const float* w1    = (const float*)d_in[4];
    const float* b1    = (const float*)d_in[5];
    const float* w2    = (const float*)d_in[6];
    const float* b2    = (const float*)d_in[7];

    float* out = (float*)d_out;             // [16384] node outputs
    float* adj = out + N_NODES;             // [16384 x 16384] adjacency as 0/1 floats
    int* flag = (int*)d_ws;

    mlp_kernel<<<N_NODES / 4, 256, 0, stream>>>(z, emb, w1, b1, w2, b2,
                                                (const int*)batch, flag, out);
    adj_kernel<<<dim3(N_NODES / TJ, N_NODES / TI), 256, 0, stream>>>(pos, batch, flag, adj);
}